// Round 3
// baseline (121.209 us; speedup 1.0000x reference)
//
#include <hip/hip_runtime.h>

// upfirdn2d: up=1, down=2, 4x4 kernel, pad=(1,1)
// x: (8,128,256,256) f32 ; kernel: (4,4) f32 ; out: (8,128,128,128) f32
//
// out[n,c,oh,ow] = sum_{i,j} x[n,c, 2*oh+i-1, 2*ow+j-1] * kflip[i][j]
//
// One wave = 8 output rows x full width. Each input row is one fully
// coalesced wave load (64 lanes x float4 = 1 KiB = whole row). Column halo
// via __shfl with neighbor lanes. Lane -> output cols {2l, 2l+1}.
//
// __launch_bounds__(256, 6): request 6 blocks/CU (24 waves/CU) -> VGPR <= ~80
// for deeper read-latency hiding (reads need MLP; 4 waves/SIMD was marginal).
//
// XCD swizzle: blockIdx round-robins across the 8 XCDs; remap so each XCD
// owns 128 consecutive images -> all 4 slab-blocks of an image share one L2,
// making the 2-row inter-slab halos L2 hits instead of HBM refetch.

#define XH 256
#define XW 256
#define OH 128
#define OW 128

__global__ __launch_bounds__(256, 6) void downfir2_kernel(
    const float* __restrict__ x, const float* __restrict__ k,
    float* __restrict__ out) {
  // bijective XCD swizzle: nwg = 4096 = 8 * 512
  const int bid = (blockIdx.x & 7) * 512 + (blockIdx.x >> 3);
  const int lane = threadIdx.x & 63;
  const int wv   = threadIdx.x >> 6;   // 0..3
  const int img  = bid >> 2;           // 0..1023  (n*C + c)
  const int slab = bid & 3;            // 0..3 -> 32 output rows each
  const int oh0  = slab * 32 + wv * 8; // this wave's first output row

  // flipped kernel weights; uniform loads -> scalar regs
  float w[4][4];
#pragma unroll
  for (int i = 0; i < 4; ++i)
#pragma unroll
    for (int j = 0; j < 4; ++j) w[i][j] = k[(3 - i) * 4 + (3 - j)];

  const float* xim = x + (size_t)img * (XH * XW);
  float* oim = out + (size_t)img * (OH * OW);

  float acc[8][2];
#pragma unroll
  for (int r = 0; r < 8; ++r) { acc[r][0] = 0.f; acc[r][1] = 0.f; }

  // input rows needed: ih in [2*oh0 - 1, 2*oh0 + 16]  (18 rows)
  const int rowbase = 2 * oh0 - 1;
#pragma unroll
  for (int s = 0; s < 18; ++s) {
    const int ih = rowbase + s;        // wave-uniform
    float4 v = make_float4(0.f, 0.f, 0.f, 0.f);
    if (ih >= 0 && ih < XH)            // zero-pad rows (uniform branch)
      v = *reinterpret_cast<const float4*>(xim + (size_t)ih * XW + 4 * lane);

    // column halo: iw = 4l-1 from lane l-1 (.w), iw = 4l+4 from lane l+1 (.x)
    float left  = __shfl_up(v.w, 1);
    float right = __shfl_down(v.x, 1);
    if (lane == 0)  left  = 0.f;       // iw = -1   -> pad
    if (lane == 63) right = 0.f;       // iw = 256  -> pad

    // row s contributes to output row r iff i = s - 2r in [0,3]
#pragma unroll
    for (int r = 0; r < 8; ++r) {
      const int i = s - 2 * r;
      if (i < 0 || i > 3) continue;    // compile-time after unroll
      float a0 = acc[r][0], a1 = acc[r][1];
      // ow = 2l   : iw = 4l-1 .. 4l+2 = {left, v.x, v.y, v.z}
      a0 = fmaf(w[i][0], left, a0);
      a0 = fmaf(w[i][1], v.x, a0);
      a0 = fmaf(w[i][2], v.y, a0);
      a0 = fmaf(w[i][3], v.z, a0);
      // ow = 2l+1 : iw = 4l+1 .. 4l+4 = {v.y, v.z, v.w, right}
      a1 = fmaf(w[i][0], v.y, a1);
      a1 = fmaf(w[i][1], v.z, a1);
      a1 = fmaf(w[i][2], v.w, a1);
      a1 = fmaf(w[i][3], right, a1);
      acc[r][0] = a0; acc[r][1] = a1;
    }
  }

  // store: wave writes 8 full output rows, 8 B/lane contiguous
#pragma unroll
  for (int r = 0; r < 8; ++r) {
    float2 o;
    o.x = acc[r][0];
    o.y = acc[r][1];
    *reinterpret_cast<float2*>(oim + (size_t)(oh0 + r) * OW + 2 * lane) = o;
  }
}

extern "C" void kernel_launch(void* const* d_in, const int* in_sizes, int n_in,
                              void* d_out, int out_size, void* d_ws, size_t ws_size,
                              hipStream_t stream) {
  const float* x = (const float*)d_in[0];
  const float* k = (const float*)d_in[1];
  float* out = (float*)d_out;

  // 1024 images x 4 slabs = 4096 blocks, 256 threads (4 waves) each
  dim3 grid(8 * 128 * 4);
  dim3 block(256);
  downfir2_kernel<<<grid, block, 0, stream>>>(x, k, out);
}

// Round 5
// 61.926 us; speedup vs baseline: 1.9573x; 1.9573x over previous
//
#include <hip/hip_runtime.h>

// upfirdn2d: up=1, down=2, 4x4 kernel, pad=(1,1)
// x: (8,128,256,256) f32 ; kernel: (4,4) f32 ; out: (8,128,128,128) f32
//
// out[n,c,oh,ow] = sum_{i,j} x[n,c, 2*oh+i-1, 2*ow+j-1] * kflip[i][j]
//
// One wave = 8 output rows x full width. Each input row is one fully
// coalesced wave load (64 lanes x float4 = 1 KiB = whole row). Column halo
// via __shfl with neighbor lanes. Lane -> output cols {2l, 2l+1}.
//
// All 18 row loads are issued unguarded with CLAMPED (always in-bounds,
// aligned) addresses -> 18 KiB in flight per wave for HBM latency hiding.
// Out-of-range rows are zeroed by a branchless per-row select (v_cndmask),
// not a branch: straight-line body, no CFG around the load pipeline.

#define XH 256
#define XW 256
#define OH 128
#define OW 128

__global__ __launch_bounds__(256) void downfir2_kernel(
    const float* __restrict__ x, const float* __restrict__ k,
    float* __restrict__ out) {
  const int lane = threadIdx.x & 63;
  const int wv   = threadIdx.x >> 6;   // 0..3
  const int bid  = blockIdx.x;
  const int img  = bid >> 2;           // 0..1023  (n*C + c)
  const int slab = bid & 3;            // 0..3 -> 32 output rows each
  const int oh0  = slab * 32 + wv * 8; // this wave's first output row

  // flipped kernel weights; uniform loads -> scalar regs
  float w[4][4];
#pragma unroll
  for (int i = 0; i < 4; ++i)
#pragma unroll
    for (int j = 0; j < 4; ++j) w[i][j] = k[(3 - i) * 4 + (3 - j)];

  const float* xim = x + (size_t)img * (XH * XW);
  float* oim = out + (size_t)img * (OH * OW);

  // input rows needed: ih in [2*oh0 - 1, 2*oh0 + 16]  (18 rows)
  const int rowbase = 2 * oh0 - 1;
  const float* base = xim + 4 * lane;

  // Issue all 18 row loads unguarded (clamped addresses), then branchless
  // zero-select for padded rows.
  float4 rv[18];
#pragma unroll
  for (int s = 0; s < 18; ++s) {
    const int ih = rowbase + s;
    const int ihc = ih < 0 ? 0 : (ih > XH - 1 ? XH - 1 : ih);
    rv[s] = *reinterpret_cast<const float4*>(base + (size_t)ihc * XW);
  }
#pragma unroll
  for (int s = 0; s < 18; ++s) {
    const int ih = rowbase + s;
    const bool valid = (ih >= 0) && (ih < XH);
    rv[s].x = valid ? rv[s].x : 0.f;
    rv[s].y = valid ? rv[s].y : 0.f;
    rv[s].z = valid ? rv[s].z : 0.f;
    rv[s].w = valid ? rv[s].w : 0.f;
  }

  float acc[8][2];
#pragma unroll
  for (int r = 0; r < 8; ++r) { acc[r][0] = 0.f; acc[r][1] = 0.f; }

#pragma unroll
  for (int s = 0; s < 18; ++s) {
    const float4 v = rv[s];
    // column halo: iw = 4l-1 from lane l-1 (.w), iw = 4l+4 from lane l+1 (.x)
    float left  = __shfl_up(v.w, 1);
    float right = __shfl_down(v.x, 1);
    if (lane == 0)  left  = 0.f;       // iw = -1   -> pad
    if (lane == 63) right = 0.f;       // iw = 256  -> pad

    // row s contributes to output row r iff i = s - 2r in [0,3]
#pragma unroll
    for (int r = 0; r < 8; ++r) {
      const int i = s - 2 * r;
      if (i < 0 || i > 3) continue;    // compile-time after unroll
      float a0 = acc[r][0], a1 = acc[r][1];
      // ow = 2l   : iw = 4l-1 .. 4l+2 = {left, v.x, v.y, v.z}
      a0 = fmaf(w[i][0], left, a0);
      a0 = fmaf(w[i][1], v.x, a0);
      a0 = fmaf(w[i][2], v.y, a0);
      a0 = fmaf(w[i][3], v.z, a0);
      // ow = 2l+1 : iw = 4l+1 .. 4l+4 = {v.y, v.z, v.w, right}
      a1 = fmaf(w[i][0], v.y, a1);
      a1 = fmaf(w[i][1], v.z, a1);
      a1 = fmaf(w[i][2], v.w, a1);
      a1 = fmaf(w[i][3], right, a1);
      acc[r][0] = a0; acc[r][1] = a1;
    }
  }

  // store: wave writes 8 full output rows, 8 B/lane contiguous
#pragma unroll
  for (int r = 0; r < 8; ++r) {
    float2 o;
    o.x = acc[r][0];
    o.y = acc[r][1];
    *reinterpret_cast<float2*>(oim + (size_t)(oh0 + r) * OW + 2 * lane) = o;
  }
}

extern "C" void kernel_launch(void* const* d_in, const int* in_sizes, int n_in,
                              void* d_out, int out_size, void* d_ws, size_t ws_size,
                              hipStream_t stream) {
  const float* x = (const float*)d_in[0];
  const float* k = (const float*)d_in[1];
  float* out = (float*)d_out;

  // 1024 images x 4 slabs = 4096 blocks, 256 threads (4 waves) each
  dim3 grid(8 * 128 * 4);
  dim3 block(256);
  downfir2_kernel<<<grid, block, 0, stream>>>(x, k, out);
}

// Round 6
// 58.968 us; speedup vs baseline: 2.0555x; 1.0502x over previous
//
#include <hip/hip_runtime.h>

// upfirdn2d: up=1, down=2, 4x4 kernel, pad=(1,1)
// x: (8,128,256,256) f32 ; kernel: (4,4) f32 ; out: (8,128,128,128) f32
//
// out[n,c,oh,ow] = sum_{i,j} x[n,c, 2*oh+i-1, 2*ow+j-1] * kflip[i][j]
//
// One wave = 4 output rows x full width (smaller tile than round 5 to cut
// VGPR ~115 -> ~60 and double resident waves/SIMD 4 -> 8). Each input row is
// one fully coalesced wave load (64 lanes x float4 = whole 1 KiB row); all
// 10 row loads issue unguarded with clamped in-bounds addresses, padded rows
// zeroed by branchless selects. Column halo via __shfl. Kernel weights are
// forced into SGPRs via readfirstlane (wave-uniform) to free 16 VGPRs.

#define XH 256
#define XW 256
#define OH 128
#define OW 128

__device__ __forceinline__ float uni(float v) {
  return __uint_as_float(__builtin_amdgcn_readfirstlane(__float_as_uint(v)));
}

__global__ __launch_bounds__(256) void downfir2_kernel(
    const float* __restrict__ x, const float* __restrict__ k,
    float* __restrict__ out) {
  const int lane = threadIdx.x & 63;
  const int wv   = threadIdx.x >> 6;   // 0..3
  const int bid  = blockIdx.x;
  const int img  = bid >> 3;           // 0..1023  (n*C + c)
  const int sub  = bid & 7;            // 0..7 -> 16 output rows each
  const int oh0  = sub * 16 + wv * 4;  // this wave's first output row

  // flipped kernel weights, wave-uniform -> SGPRs
  float w[4][4];
#pragma unroll
  for (int i = 0; i < 4; ++i)
#pragma unroll
    for (int j = 0; j < 4; ++j) w[i][j] = uni(k[(3 - i) * 4 + (3 - j)]);

  const float* xim = x + (size_t)img * (XH * XW);
  float* oim = out + (size_t)img * (OH * OW);

  // input rows needed: ih in [2*oh0 - 1, 2*oh0 + 8]  (10 rows)
  const int rowbase = 2 * oh0 - 1;
  const float* base = xim + 4 * lane;

  // issue all 10 row loads unguarded (clamped, aligned, in-bounds)
  float4 rv[10];
#pragma unroll
  for (int s = 0; s < 10; ++s) {
    const int ih = rowbase + s;
    const int ihc = ih < 0 ? 0 : (ih > XH - 1 ? XH - 1 : ih);
    rv[s] = *reinterpret_cast<const float4*>(base + (size_t)ihc * XW);
  }
  // branchless zero for padded rows (only edge waves have any)
#pragma unroll
  for (int s = 0; s < 10; ++s) {
    const int ih = rowbase + s;
    const bool valid = (ih >= 0) && (ih < XH);
    rv[s].x = valid ? rv[s].x : 0.f;
    rv[s].y = valid ? rv[s].y : 0.f;
    rv[s].z = valid ? rv[s].z : 0.f;
    rv[s].w = valid ? rv[s].w : 0.f;
  }

  float acc[4][2];
#pragma unroll
  for (int r = 0; r < 4; ++r) { acc[r][0] = 0.f; acc[r][1] = 0.f; }

#pragma unroll
  for (int s = 0; s < 10; ++s) {
    const float4 v = rv[s];
    // column halo: iw = 4l-1 from lane l-1 (.w), iw = 4l+4 from lane l+1 (.x)
    float left  = __shfl_up(v.w, 1);
    float right = __shfl_down(v.x, 1);
    if (lane == 0)  left  = 0.f;       // iw = -1  -> pad
    if (lane == 63) right = 0.f;       // iw = 256 -> pad

    // row s contributes to output row r iff i = s - 2r in [0,3]
#pragma unroll
    for (int r = 0; r < 4; ++r) {
      const int i = s - 2 * r;
      if (i < 0 || i > 3) continue;    // compile-time after unroll
      float a0 = acc[r][0], a1 = acc[r][1];
      // ow = 2l   : iw = 4l-1 .. 4l+2 = {left, v.x, v.y, v.z}
      a0 = fmaf(w[i][0], left, a0);
      a0 = fmaf(w[i][1], v.x, a0);
      a0 = fmaf(w[i][2], v.y, a0);
      a0 = fmaf(w[i][3], v.z, a0);
      // ow = 2l+1 : iw = 4l+1 .. 4l+4 = {v.y, v.z, v.w, right}
      a1 = fmaf(w[i][0], v.y, a1);
      a1 = fmaf(w[i][1], v.z, a1);
      a1 = fmaf(w[i][2], v.w, a1);
      a1 = fmaf(w[i][3], right, a1);
      acc[r][0] = a0; acc[r][1] = a1;
    }
  }

  // store: wave writes 4 full output rows, 8 B/lane contiguous
#pragma unroll
  for (int r = 0; r < 4; ++r) {
    float2 o;
    o.x = acc[r][0];
    o.y = acc[r][1];
    *reinterpret_cast<float2*>(oim + (size_t)(oh0 + r) * OW + 2 * lane) = o;
  }
}

extern "C" void kernel_launch(void* const* d_in, const int* in_sizes, int n_in,
                              void* d_out, int out_size, void* d_ws, size_t ws_size,
                              hipStream_t stream) {
  const float* x = (const float*)d_in[0];
  const float* k = (const float*)d_in[1];
  float* out = (float*)d_out;

  // 1024 images x 8 sub-slabs = 8192 blocks, 256 threads (4 waves) each
  dim3 grid(8 * 128 * 8);
  dim3 block(256);
  downfir2_kernel<<<grid, block, 0, stream>>>(x, k, out);
}